// Round 1
// baseline (1332.023 us; speedup 1.0000x reference)
//
#include <hip/hip_runtime.h>
#include <math.h>

#define LEVELS 16
#define MAX_RES 2048

struct ResParams { int res[LEVELS]; };

__global__ __launch_bounds__(256) void triplane_kernel(
    const float* __restrict__ positions,
    const float* __restrict__ table,
    float* __restrict__ out,
    ResParams P, int B)
{
  int gid = blockIdx.x * 256 + threadIdx.x;
  int b = gid >> 4;          // point index: lanes 0-15 share a point
  int l = gid & 15;          // level index
  if (b >= B) return;

  float x = positions[b*3 + 0];
  float y = positions[b*3 + 1];
  float z = positions[b*3 + 2];

  int   res   = P.res[l];
  float resm1 = (float)(res - 1);
  float fres  = (float)res;

  // plane p uses (u,v) = (x,y), (y,z), (z,x)
  float uarr[3] = {x, y, z};
  float varr[3] = {y, z, x};

  float prod0 = 1.0f, prod1 = 1.0f;

  #pragma unroll
  for (int p = 0; p < 3; ++p) {
    // pos = u*(res-1) + 0.5  -- separate mul/add roundings to match numpy (no FMA)
    float pu = __fadd_rn(__fmul_rn(uarr[p], resm1), 0.5f);
    float pv = __fadd_rn(__fmul_rn(varr[p], resm1), 0.5f);
    float gu = floorf(pu), gv = floorf(pv);
    float fu = __fsub_rn(pu, gu);
    float fv = __fsub_rn(pv, gv);

    const float* plane = table + (size_t)p * (MAX_RES * MAX_RES * 2);

    float acc0 = 0.0f, acc1 = 0.0f;
    #pragma unroll
    for (int idx = 0; idx < 4; ++idx) {
      float cu = gu + (float)(idx & 1);
      float cv = gv + (float)((idx >> 1) & 1);
      float wu = (idx & 1) ? fu : (1.0f - fu);
      float wv = (idx & 2) ? fv : (1.0f - fv);
      float w  = wu * wv;

      // c_ori = trunc((c / res) * 2047)  -- IEEE div + mul, truncate (matches astype(int32))
      int cou = (int)(__fmul_rn(cu / fres, 2047.0f));
      int cov = (int)(__fmul_rn(cv / fres, 2047.0f));
      int idx2 = cou + (cov << 11);

      const float2 f = *reinterpret_cast<const float2*>(plane + (size_t)idx2 * 2);
      acc0 += w * f.x;
      acc1 += w * f.y;
    }
    prod0 *= acc0;
    prod1 *= acc1;
  }

  // out[b, f, l] flattened as b*32 + f*16 + l
  out[(size_t)b * 32 + l]      = prod0;
  out[(size_t)b * 32 + 16 + l] = prod1;
}

extern "C" void kernel_launch(void* const* d_in, const int* in_sizes, int n_in,
                              void* d_out, int out_size, void* d_ws, size_t ws_size,
                              hipStream_t stream) {
  const float* positions = (const float*)d_in[0];
  const float* table     = (const float*)d_in[1];
  float* out             = (float*)d_out;
  int B = in_sizes[0] / 3;

  // Reproduce the Python host-side res computation bit-exactly (same libm).
  ResParams P;
  const double LOG_B = log(2048.0 / 16.0) / (double)(LEVELS - 1);
  for (int l = 0; l < LEVELS; ++l) {
    double scale = 16.0 * exp((double)l * LOG_B) - 1.0;
    P.res[l] = (int)ceil(scale) + 1;
  }

  int total  = B * LEVELS;
  int blocks = (total + 255) / 256;
  hipLaunchKernelGGL(triplane_kernel, dim3(blocks), dim3(256), 0, stream,
                     positions, table, out, P, B);
}